// Round 4
// baseline (137.941 us; speedup 1.0000x reference)
//
#include <hip/hip_runtime.h>
#include <hip/hip_bf16.h>

// out[b,k] = sum_{i,j} x[b,i] * W[k,i,j] * x[b,j]
// GEMM P (B x 160 XOR-classed pair-products) @ Q (160 x 16),
// 5 x mfma_f32_16x16x32_bf16 per 16-row tile.
//
// R9: R5 dataflow + (256,8) envelope (R7: occupancy > per-wave ILP), with
// EVERY DS-pipe op removed from the loop — using only plain address
// arithmetic (R6/R8 lesson: no unverifiable cross-lane semantics).
//   load : 3 x global_load_dwordx4 per lane (chunks q, q^1, q^2 of row n)
//          instead of 1 load + 8 ds_bpermute. Same cache lines the wave
//          already fetches -> MSHR-coalesced, arrive together; chain head
//          is ONE memory latency, no lgkm round-trip. L1/L2 absorb the 3x
//          re-read (HBM traffic unchanged).
//   store: 4 x global_store_dword at ob + r*16 floats (imm offsets
//          0/64/128/192B) instead of the Tb LDS transpose. Derived from
//          R5's VERIFIED transpose indices: lane(n,q) reg r holds
//          out[tile + (4q+r)*16 + n]. Each store = 4 coalesced 64B
//          segments. Kills 4 ds_write + 1 ds_read + lgkm wait + the
//          same-wave WAR serialization between tiles + all 688K
//          bank-conflict cycles. Tb deleted (LDS 10240 -> 5120B).
//   acc  : split 3+2 MFMA chains + one v4 add (halves serial MFMA latency;
//          fp32 reorder only, << 0.225 threshold).
//
// XOR class algebra unchanged (orbit-enumeration verified): K-slot
// k = 32s+8q+j holds, at lane quad q, x[alpha_c^4q]*x[beta_c^4q], c=8s+j;
// 120 off-diag pairs net weight 1, 16 diagonals once. xv[v] = x[n][v^4q]:
// slot s of xv = raw chunk s^q, so xv[4+e] = x[n][4(q^1)+e] etc.

typedef __attribute__((ext_vector_type(8)))  short  short8;
typedef __attribute__((ext_vector_type(8)))  __bf16 bf16x8;
typedef __attribute__((ext_vector_type(4)))  float  floatx4;

#define DEV static __device__ __forceinline__

// ---- XOR class table ----
constexpr int cA(int c) {            // alpha
    if (c < 24) { const int dIdx = c >> 1, v = c & 1;
        const int hi = dIdx / 3, lo = dIdx % 3 + 1;
        const int base = (hi == 3) ? 1 : 0;
        const int l = v ? ((lo == 1) ? 2 : 1) : 0;
        return base * 4 + l; }
    if (c < 36) { const int g = c - 24, hi = g / 4 + 1, l = g & 3;
        const int base = (hi == 3) ? 1 : 0;
        return base * 4 + l; }
    return c - 36;
}
constexpr int cDd(int c) {           // d = alpha ^ beta
    if (c < 24) { const int dIdx = c >> 1;
        return (dIdx / 3) * 4 + (dIdx % 3 + 1); }
    if (c < 36) { return ((c - 24) / 4 + 1) * 4; }
    return 0;
}
constexpr int   cB(int c) { return cA(c) ^ cDd(c); }
constexpr float cW(int c) { return (c >= 24 && c < 36) ? 0.5f : 1.0f; }

template <int C>
DEV float pval(const float* xv) {    // xv indexed directly by value id (<=11)
    return xv[cA(C)] * xv[cB(C)];
}

template <int S>   // frag S covers classes c = 8S .. 8S+7
DEV short8 make_afrag(const float* xv) {
    union { short8 s; __hip_bfloat162 h[4]; } u;
    u.h[0] = __float22bfloat162_rn(make_float2(pval<8 * S + 0>(xv), pval<8 * S + 1>(xv)));
    u.h[1] = __float22bfloat162_rn(make_float2(pval<8 * S + 2>(xv), pval<8 * S + 3>(xv)));
    u.h[2] = __float22bfloat162_rn(make_float2(pval<8 * S + 4>(xv), pval<8 * S + 5>(xv)));
    u.h[3] = __float22bfloat162_rn(make_float2(pval<8 * S + 6>(xv), pval<8 * S + 7>(xv)));
    return u.s;
}

DEV floatx4 mfma_bf16(short8 a, short8 b, floatx4 c) {
    return __builtin_amdgcn_mfma_f32_16x16x32_bf16(
        __builtin_bit_cast(bf16x8, a), __builtin_bit_cast(bf16x8, b), c, 0, 0, 0);
}

// ---- Q element for flat slot e = n*160 + k,  k = 32s + 8q + j ----
DEV float q_elem(const float* __restrict__ W, int e) {
    const int n = e / 160;
    const int k = e - n * 160;
    const int s = k >> 5, q = (k >> 3) & 3, j = k & 7;
    const int c = 8 * s + j;
    const int I = cA(c) ^ (q << 2);
    const int J = cB(c) ^ (q << 2);
    return (I == J) ? W[n * 256 + I * 16 + I]
                    : cW(c) * (W[n * 256 + I * 16 + J] + W[n * 256 + J * 16 + I]);
}

__global__ __launch_bounds__(256, 8)
void bilinear16_kernel(const float* __restrict__ x, const float* __restrict__ W,
                       float* __restrict__ out, int ntiles) {
    __shared__ __align__(16) short Qt[16][160];   // 5120 B — the ONLY LDS

    const int tid = threadIdx.x;
    for (int e = tid; e < 16 * 160; e += 256) {
        __hip_bfloat16 h = __float2bfloat16(q_elem(W, e));
        Qt[0][e] = *reinterpret_cast<short*>(&h);
    }
    __syncthreads();

    const int lane = tid & 63;
    const int n    = lane & 15;   // row within tile for loads; channel for stores
    const int q    = lane >> 4;   // chunk / k-group quad

    // B-frags (20 VGPRs), resident across the loop.
    const short8 b0 = *reinterpret_cast<const short8*>(&Qt[n][0 * 32 + q * 8]);
    const short8 b1 = *reinterpret_cast<const short8*>(&Qt[n][1 * 32 + q * 8]);
    const short8 b2 = *reinterpret_cast<const short8*>(&Qt[n][2 * 32 + q * 8]);
    const short8 b3 = *reinterpret_cast<const short8*>(&Qt[n][3 * 32 + q * 8]);
    const short8 b4 = *reinterpret_cast<const short8*>(&Qt[n][4 * 32 + q * 8]);

    const int waveId = blockIdx.x * 4 + (tid >> 6);
    const int nwaves = gridDim.x * 4;

    for (int t = waveId; t < ntiles; t += nwaves) {
        // 3 independent coalesced loads: raw chunks q, q^1, q^2 of row n.
        // (Same 1KB tile the wave covers; extra reads are L1/MSHR hits.)
        const float* xt = x + (size_t)t * 256 + n * 16;
        const float4 v0 = *reinterpret_cast<const float4*>(xt + q * 4);
        const float4 v1 = *reinterpret_cast<const float4*>(xt + (q ^ 1) * 4);
        const float4 v2 = *reinterpret_cast<const float4*>(xt + (q ^ 2) * 4);
        // xv[v] = x[n][v ^ 4q]: local slot s = raw chunk s^q.
        const float xv[12] = {v0.x, v0.y, v0.z, v0.w,
                              v1.x, v1.y, v1.z, v1.w,
                              v2.x, v2.y, v2.z, v2.w};

        // Two independent accumulator chains (3+2 MFMAs), merged at the end.
        floatx4 acc0 = {0.f, 0.f, 0.f, 0.f};
        floatx4 acc1 = {0.f, 0.f, 0.f, 0.f};
        acc0 = mfma_bf16(make_afrag<0>(xv), b0, acc0);
        acc1 = mfma_bf16(make_afrag<1>(xv), b1, acc1);
        acc0 = mfma_bf16(make_afrag<2>(xv), b2, acc0);
        acc1 = mfma_bf16(make_afrag<3>(xv), b3, acc1);
        acc0 = mfma_bf16(make_afrag<4>(xv), b4, acc0);
        acc0 = acc0 + acc1;

        // Direct store, no LDS: lane(n,q) reg r holds out[(4q+r)*16 + n]
        // (derived from R5's verified transpose indices). One address reg,
        // imm offsets 0/64/128/192B; each store = 4 coalesced 64B segments.
        float* ob = out + (size_t)t * 256 + q * 64 + n;
        ob[0]  = acc0[0];
        ob[16] = acc0[1];
        ob[32] = acc0[2];
        ob[48] = acc0[3];
    }
}

extern "C" void kernel_launch(void* const* d_in, const int* in_sizes, int n_in,
                              void* d_out, int out_size, void* d_ws, size_t ws_size,
                              hipStream_t stream) {
    const float* x = (const float*)d_in[0];
    const float* W = (const float*)d_in[1];
    float* out = (float*)d_out;
    const int Bn = in_sizes[0] / 16;   // 1048576
    const int ntiles = Bn >> 4;        // 65536
    // 2048 blocks x 4 waves = 8192 waves; 8 tiles/wave exactly.
    bilinear16_kernel<<<2048, 256, 0, stream>>>(x, W, out, ntiles);
}

// Round 5
// 122.878 us; speedup vs baseline: 1.1226x; 1.1226x over previous
//
#include <hip/hip_runtime.h>
#include <hip/hip_bf16.h>

// out[b,k] = sum_{i,j} x[b,i] * W[k,i,j] * x[b,j]
// GEMM P (B x 160 XOR-classed pair-products) @ Q (160 x 16),
// 5 x mfma_f32_16x16x32_bf16 per 16-row tile.
//
// R10: R5 memory shape EXACTLY (1 dwordx4 load + 8 bpermute + LDS
// transpose + 1 dwordx4 store — R9 proved scalar stores inflate WRITE 15%
// and extra VMEM ops lose), + explicit register PARTITION of the 64-reg
// (256,8) budget:
//   - b-frags (20 regs, read-only, MFMA B operand) pinned to AGPRs via
//     empty asm "+a" — MFMA reads B/C/D from AGPR natively on gfx950
//     (AV_* operand classes), zero copy cost.
//   - frees ~20 arch VGPRs for the VALU-hot transients (xv, products,
//     bf16 packing), killing the accvgpr spill-copy bloat that made
//     measured VALU ~650 cy/tile vs the ~120 cy arithmetic floor
//     (absolute VALU work was invariant ~17.5us across R5/R7/R9 — the
//     tell that it's allocation overhead, not algorithm).
//   - 3+2 dual accumulator chain kept (harness-verified in R9).
//
// XOR class algebra unchanged (orbit-enumeration verified): K-slot
// k = 32s+8q+j holds, at lane quad q, x[alpha_c^4q]*x[beta_c^4q], c=8s+j;
// 120 off-diag pairs net weight 1, 16 diagonals once.

typedef __attribute__((ext_vector_type(8)))  short  short8;
typedef __attribute__((ext_vector_type(8)))  __bf16 bf16x8;
typedef __attribute__((ext_vector_type(4)))  float  floatx4;

#define DEV static __device__ __forceinline__

// ---- XOR class table ----
constexpr int cA(int c) {            // alpha
    if (c < 24) { const int dIdx = c >> 1, v = c & 1;
        const int hi = dIdx / 3, lo = dIdx % 3 + 1;
        const int base = (hi == 3) ? 1 : 0;
        const int l = v ? ((lo == 1) ? 2 : 1) : 0;
        return base * 4 + l; }
    if (c < 36) { const int g = c - 24, hi = g / 4 + 1, l = g & 3;
        const int base = (hi == 3) ? 1 : 0;
        return base * 4 + l; }
    return c - 36;
}
constexpr int cDd(int c) {           // d = alpha ^ beta
    if (c < 24) { const int dIdx = c >> 1;
        return (dIdx / 3) * 4 + (dIdx % 3 + 1); }
    if (c < 36) { return ((c - 24) / 4 + 1) * 4; }
    return 0;
}
constexpr int   cB(int c) { return cA(c) ^ cDd(c); }
constexpr float cW(int c) { return (c >= 24 && c < 36) ? 0.5f : 1.0f; }

template <int C>
DEV float pval(const float* xv) {    // xv indexed directly by value id (<=11)
    return xv[cA(C)] * xv[cB(C)];
}

template <int S>   // frag S covers classes c = 8S .. 8S+7
DEV short8 make_afrag(const float* xv) {
    union { short8 s; __hip_bfloat162 h[4]; } u;
    u.h[0] = __float22bfloat162_rn(make_float2(pval<8 * S + 0>(xv), pval<8 * S + 1>(xv)));
    u.h[1] = __float22bfloat162_rn(make_float2(pval<8 * S + 2>(xv), pval<8 * S + 3>(xv)));
    u.h[2] = __float22bfloat162_rn(make_float2(pval<8 * S + 4>(xv), pval<8 * S + 5>(xv)));
    u.h[3] = __float22bfloat162_rn(make_float2(pval<8 * S + 6>(xv), pval<8 * S + 7>(xv)));
    return u.s;
}

DEV floatx4 mfma_bf16(short8 a, short8 b, floatx4 c) {
    return __builtin_amdgcn_mfma_f32_16x16x32_bf16(
        __builtin_bit_cast(bf16x8, a), __builtin_bit_cast(bf16x8, b), c, 0, 0, 0);
}

// ---- Q element for flat slot e = n*160 + k,  k = 32s + 8q + j ----
DEV float q_elem(const float* __restrict__ W, int e) {
    const int n = e / 160;
    const int k = e - n * 160;
    const int s = k >> 5, q = (k >> 3) & 3, j = k & 7;
    const int c = 8 * s + j;
    const int I = cA(c) ^ (q << 2);
    const int J = cB(c) ^ (q << 2);
    return (I == J) ? W[n * 256 + I * 16 + I]
                    : cW(c) * (W[n * 256 + I * 16 + J] + W[n * 256 + J * 16 + I]);
}

__global__ __launch_bounds__(256, 8)
void bilinear16_kernel(const float* __restrict__ x, const float* __restrict__ W,
                       float* __restrict__ out, int ntiles) {
    __shared__ __align__(16) short Qt[16][160];   // 5120 B
    __shared__ __align__(16) float Tb[4][320];    // 4 waves x (16 rows x 20 dw) = 5120 B

    const int tid = threadIdx.x;
    for (int e = tid; e < 16 * 160; e += 256) {
        __hip_bfloat16 h = __float2bfloat16(q_elem(W, e));
        Qt[0][e] = *reinterpret_cast<short*>(&h);
    }
    __syncthreads();

    const int lane = tid & 63;
    const int n    = lane & 15;   // MFMA A-row / C col (fixed by HW layout)
    const int q    = lane >> 4;   // MFMA k-group quad
    float* const tb = Tb[tid >> 6];

    // B-frags (20 regs), resident across the loop — pinned to AGPRs.
    // MFMA reads its B operand from AGPR natively (gfx950 unified file),
    // so this costs a one-time v->a copy and frees 20 arch VGPRs for the
    // VALU-hot transients below (the whole point of R10).
    short8 b0 = *reinterpret_cast<const short8*>(&Qt[n][0 * 32 + q * 8]);
    short8 b1 = *reinterpret_cast<const short8*>(&Qt[n][1 * 32 + q * 8]);
    short8 b2 = *reinterpret_cast<const short8*>(&Qt[n][2 * 32 + q * 8]);
    short8 b3 = *reinterpret_cast<const short8*>(&Qt[n][3 * 32 + q * 8]);
    short8 b4 = *reinterpret_cast<const short8*>(&Qt[n][4 * 32 + q * 8]);
    asm("" : "+a"(b0));
    asm("" : "+a"(b1));
    asm("" : "+a"(b2));
    asm("" : "+a"(b3));
    asm("" : "+a"(b4));

    const int waveId = blockIdx.x * 4 + (tid >> 6);
    const int nwaves = gridDim.x * 4;

    for (int t = waveId; t < ntiles; t += nwaves) {
        // ONE coalesced load: lane (n,q) <- chunk q of row n (tile read once).
        const float4 own = *reinterpret_cast<const float4*>(
            x + (size_t)t * 256 + n * 16 + q * 4);
        float4 s1, s2;                 // chunk q^1 from lane^16, chunk q^2 from lane^32
        s1.x = __shfl_xor(own.x, 16); s1.y = __shfl_xor(own.y, 16);
        s1.z = __shfl_xor(own.z, 16); s1.w = __shfl_xor(own.w, 16);
        s2.x = __shfl_xor(own.x, 32); s2.y = __shfl_xor(own.y, 32);
        s2.z = __shfl_xor(own.z, 32); s2.w = __shfl_xor(own.w, 32);
        const float xv[12] = {own.x, own.y, own.z, own.w,
                              s1.x,  s1.y,  s1.z,  s1.w,
                              s2.x,  s2.y,  s2.z,  s2.w};

        // Two independent accumulator chains (3+2 MFMAs), merged at the end
        // (harness-verified in R9; fp32 reorder only).
        floatx4 acc0 = {0.f, 0.f, 0.f, 0.f};
        floatx4 acc1 = {0.f, 0.f, 0.f, 0.f};
        acc0 = mfma_bf16(make_afrag<0>(xv), b0, acc0);
        acc1 = mfma_bf16(make_afrag<1>(xv), b1, acc1);
        acc0 = mfma_bf16(make_afrag<2>(xv), b2, acc0);
        acc1 = mfma_bf16(make_afrag<3>(xv), b3, acc1);
        acc0 = mfma_bf16(make_afrag<4>(xv), b4, acc0);
        acc0 = acc0 + acc1;

        // C/D layout: col = lane&15, row = q*4 + reg  [m89-verified].
        // Wave-internal LDS transpose -> lane-linear float4 store.
        tb[(q * 4 + 0) * 20 + n] = acc0[0];
        tb[(q * 4 + 1) * 20 + n] = acc0[1];
        tb[(q * 4 + 2) * 20 + n] = acc0[2];
        tb[(q * 4 + 3) * 20 + n] = acc0[3];
        const float4 o = *reinterpret_cast<const float4*>(
            &tb[(lane >> 2) * 20 + (lane & 3) * 4]);
        *reinterpret_cast<float4*>(out + (size_t)t * 256 + lane * 4) = o;
    }
}

extern "C" void kernel_launch(void* const* d_in, const int* in_sizes, int n_in,
                              void* d_out, int out_size, void* d_ws, size_t ws_size,
                              hipStream_t stream) {
    const float* x = (const float*)d_in[0];
    const float* W = (const float*)d_in[1];
    float* out = (float*)d_out;
    const int Bn = in_sizes[0] / 16;   // 1048576
    const int ntiles = Bn >> 4;        // 65536
    // 2048 blocks x 4 waves = 8192 waves; 8 tiles/wave exactly.
    bilinear16_kernel<<<2048, 256, 0, stream>>>(x, W, out, ntiles);
}